// Round 8
// baseline (8777.887 us; speedup 1.0000x reference)
//
#include <hip/hip_runtime.h>
#include <hip/hip_bf16.h>
#include <stdint.h>

// Problem constants
#define B_    2
#define S_    4096
#define H_    1024
#define NKH_  8
#define NVH_  16
#define DK_   64
#define DV_   64
#define KEYD_ 512          // NKH*DK
#define CDIM_ 2048         // 2*KEYD + VAL_DIM
#define VALD_ 1024         // NVH*DV

using bf16 = __hip_bfloat16;

__device__ inline uint16_t f2b(float f) {
  union { bf16 h; uint16_t u; } c; c.h = __float2bfloat16(f); return c.u;
}

// ---------------------------------------------------------------------------
// vgemm_fb: C[m,n] = sum_k A[m,k]*B[n,k]; A,B fp32 in, C bf16 out.
// 64x64 tile / 256 threads, 4x4/thread, fp32 accum. (r4-validated structure)
// ---------------------------------------------------------------------------
__global__ __launch_bounds__(256) void vgemm_fb(const float* __restrict__ A,
                                                const float* __restrict__ Bm,
                                                bf16* __restrict__ C,
                                                int M, int N, int K) {
  __shared__ float As[64][33];
  __shared__ float Bs[64][33];
  const int t = threadIdx.x;
  const int tx = t & 15, ty = t >> 4;
  const int ntn = N >> 6;
  const int bm = blockIdx.x / ntn, bn = blockIdx.x % ntn;
  const int m0 = bm << 6, n0 = bn << 6;
  float acc[4][4] = {};
  for (int k0 = 0; k0 < K; k0 += 32) {
    for (int i = t; i < 64 * 32; i += 256) {
      const int r = i >> 5, c = i & 31;
      As[r][c] = A[(long)(m0 + r) * K + k0 + c];
      Bs[r][c] = Bm[(long)(n0 + r) * K + k0 + c];
    }
    __syncthreads();
#pragma unroll 8
    for (int kk = 0; kk < 32; ++kk) {
      float av[4], bv[4];
#pragma unroll
      for (int i = 0; i < 4; ++i) av[i] = As[ty * 4 + i][kk];
#pragma unroll
      for (int j = 0; j < 4; ++j) bv[j] = Bs[tx * 4 + j][kk];
#pragma unroll
      for (int i = 0; i < 4; ++i)
#pragma unroll
        for (int j = 0; j < 4; ++j)
          acc[i][j] = fmaf(av[i], bv[j], acc[i][j]);
    }
    __syncthreads();
  }
#pragma unroll
  for (int i = 0; i < 4; ++i)
#pragma unroll
    for (int j = 0; j < 4; ++j)
      C[(long)(m0 + ty * 4 + i) * N + (n0 + tx * 4 + j)] =
          __float2bfloat16(acc[i][j]);
}

// vgemm_ff: same but C fp32 out (z projection and final output).
__global__ __launch_bounds__(256) void vgemm_ff(const float* __restrict__ A,
                                                const float* __restrict__ Bm,
                                                float* __restrict__ C,
                                                int M, int N, int K) {
  __shared__ float As[64][33];
  __shared__ float Bs[64][33];
  const int t = threadIdx.x;
  const int tx = t & 15, ty = t >> 4;
  const int ntn = N >> 6;
  const int bm = blockIdx.x / ntn, bn = blockIdx.x % ntn;
  const int m0 = bm << 6, n0 = bn << 6;
  float acc[4][4] = {};
  for (int k0 = 0; k0 < K; k0 += 32) {
    for (int i = t; i < 64 * 32; i += 256) {
      const int r = i >> 5, c = i & 31;
      As[r][c] = A[(long)(m0 + r) * K + k0 + c];
      Bs[r][c] = Bm[(long)(n0 + r) * K + k0 + c];
    }
    __syncthreads();
#pragma unroll 8
    for (int kk = 0; kk < 32; ++kk) {
      float av[4], bv[4];
#pragma unroll
      for (int i = 0; i < 4; ++i) av[i] = As[ty * 4 + i][kk];
#pragma unroll
      for (int j = 0; j < 4; ++j) bv[j] = Bs[tx * 4 + j][kk];
#pragma unroll
      for (int i = 0; i < 4; ++i)
#pragma unroll
        for (int j = 0; j < 4; ++j)
          acc[i][j] = fmaf(av[i], bv[j], acc[i][j]);
    }
    __syncthreads();
  }
#pragma unroll
  for (int i = 0; i < 4; ++i)
#pragma unroll
    for (int j = 0; j < 4; ++j)
      C[(long)(m0 + ty * 4 + i) * N + (n0 + tx * 4 + j)] = acc[i][j];
}

// ---------------------------------------------------------------------------
// conv2: causal depthwise k=4 (cross-corr, XLA, no flip), silu, q-scale.
// ---------------------------------------------------------------------------
__global__ __launch_bounds__(256) void conv2(const bf16* __restrict__ mixed,
                                             const float* __restrict__ cw,
                                             bf16* __restrict__ qkv) {
  const long idx = (long)blockIdx.x * 256 + threadIdx.x;  // M*2048
  const int c = (int)(idx & (CDIM_ - 1));
  const long row = idx >> 11;
  const int s = (int)(row & (S_ - 1));
  float acc = 0.f;
#pragma unroll
  for (int j = 0; j < 4; ++j) {
    const int ss = s - 3 + j;
    if (ss >= 0)
      acc = fmaf(cw[c * 4 + j], (float)mixed[(row + j - 3) * CDIM_ + c], acc);
  }
  float y = acc / (1.f + __expf(-acc));        // silu
  if (c < KEYD_) y *= 0.125f;                  // q * DK^-0.5
  ((uint16_t*)qkv)[row * CDIM_ + c] = f2b(y);
}

// ---------------------------------------------------------------------------
// projbg: one thread per (row, j). All fp32.
// ---------------------------------------------------------------------------
__global__ __launch_bounds__(256) void projbg(const float* __restrict__ hs,
                                              const float* __restrict__ Wb,
                                              const float* __restrict__ Wa,
                                              const float* __restrict__ dtb,
                                              const float* __restrict__ Alog,
                                              float* __restrict__ beta,
                                              float* __restrict__ g) {
  const long idx = (long)blockIdx.x * 256 + threadIdx.x;  // M*32
  const int j = (int)(idx & 31);
  const long row = idx >> 5;
  const float* hp = hs + row * H_;
  const float* wp = (j < 16) ? (Wb + (long)j * H_) : (Wa + (long)(j - 16) * H_);
  float acc = 0.f;
  for (int i = 0; i < H_; ++i) acc = fmaf(hp[i], wp[i], acc);
  if (j < 16) {
    beta[row * NVH_ + j] = 1.f / (1.f + __expf(-acc));
  } else {
    const int hh = j - 16;
    const float x = acc + dtb[hh];
    const float sp = (x > 20.f) ? x : log1pf(__expf(x));
    g[row * NVH_ + hh] = -__expf(Alog[hh]) * sp;
  }
}

// ---------------------------------------------------------------------------
// scan2: one 64-lane wave per (b,h). lane = dv; S[dk][dv=lane] in registers;
// k/q broadcast via __shfl. (r5/r6-validated)
// ---------------------------------------------------------------------------
__global__ __launch_bounds__(64) void scan2(const bf16* __restrict__ qkv,
                                            const float* __restrict__ beta,
                                            const float* __restrict__ g,
                                            float* __restrict__ o) {
  const int bh = blockIdx.x;              // 0..31
  const int b = bh >> 4, h = bh & 15;
  const int l = threadIdx.x;
  const int kh = h >> 1;                  // GQA repeat_interleave(2)
  const bf16* base = qkv + (long)b * S_ * CDIM_;
  const bf16* qp = base + kh * 64 + l;
  const bf16* kp = base + KEYD_ + kh * 64 + l;
  const bf16* vp = base + 2 * KEYD_ + h * 64 + l;
  const float* gp = g + (long)b * S_ * NVH_ + h;
  const float* bp = beta + (long)b * S_ * NVH_ + h;
  float* op = o + ((long)b * S_ * NVH_ + h) * 64 + l;

  float S[64];
#pragma unroll
  for (int i = 0; i < 64; ++i) S[i] = 0.f;

  float kc = (float)kp[0], qc = (float)qp[0], vc = (float)vp[0];
  float gc = gp[0], bc = bp[0];
  for (int t = 0; t < S_; ++t) {
    const int tn = (t + 1 < S_) ? t + 1 : t;
    const long on = (long)tn * CDIM_;
    float kn = (float)kp[on], qn = (float)qp[on], vn = (float)vp[on];
    float gn = gp[(long)tn * NVH_], bn = bp[(long)tn * NVH_];

    const float eg = __expf(gc);
    float kv = 0.f;
#pragma unroll
    for (int j = 0; j < 64; ++j) {
      const float kj = __shfl(kc, j);
      S[j] *= eg;
      kv = fmaf(S[j], kj, kv);
    }
    const float dl = (vc - kv) * bc;
    float ov = 0.f;
#pragma unroll
    for (int j = 0; j < 64; ++j) {
      const float kj = __shfl(kc, j);
      const float qj = __shfl(qc, j);
      S[j] = fmaf(kj, dl, S[j]);
      ov = fmaf(S[j], qj, ov);
    }
    op[(long)t * VALD_] = ov;

    kc = kn; qc = qn; vc = vn; gc = gn; bc = bn;
  }
}

// ---------------------------------------------------------------------------
// gnorm2: one thread per (b,s,h) row of 64. o fp32, z fp32 -> hn fp32.
// ---------------------------------------------------------------------------
__global__ __launch_bounds__(256) void gnorm2(const float* __restrict__ o,
                                              const float* __restrict__ z,
                                              const float* __restrict__ nw,
                                              float* __restrict__ hn) {
  const long idx = (long)blockIdx.x * 256 + threadIdx.x;  // M*16
  const float* op = o + idx * 64;
  const float* zp = z + idx * 64;
  float hv[64];
  float ss = 0.f;
#pragma unroll
  for (int i = 0; i < 64; ++i) {
    const float zz = zp[i];
    const float hh = op[i] * (zz / (1.f + __expf(-zz)));
    hv[i] = hh;
    ss = fmaf(hh, hh, ss);
  }
  const float r = rsqrtf(ss * (1.f / 64.f) + 1e-6f);
#pragma unroll
  for (int i = 0; i < 64; ++i)
    hn[idx * 64 + i] = hv[i] * r * nw[i];
}

// ---------------------------------------------------------------------------
extern "C" void kernel_launch(void* const* d_in, const int* in_sizes, int n_in,
                              void* d_out, int out_size, void* d_ws, size_t ws_size,
                              hipStream_t stream) {
  float* out = (float*)d_out;   // *** fp32 output (round-8 fix) ***
  const int M = B_ * S_;        // 8192

  // input mapping (r7: dict order confirmed by in_sizes signature; keep
  // size-based fallback for safety)
  int ih, iqkv, icw, iz, ib, ia, idtb, ialog, inw, iout;
  if (n_in >= 10 && in_sizes[0] == 8388608) {
    ih = 0; iqkv = 1; icw = 2; iz = 3; ib = 4; ia = 5;
    idtb = 6; ialog = 7; inw = 8; iout = 9;
  } else {
    ih = iqkv = icw = iz = ib = ia = idtb = ialog = inw = iout = -1;
    for (int i = 0; i < n_in; ++i) {
      switch (in_sizes[i]) {
        case 8388608: ih = i; break;
        case 2097152: iqkv = i; break;
        case 8192:    icw = i; break;
        case 64:      inw = i; break;
        case 1048576: if (iz < 0) iz = i; else iout = i; break;
        case 16384:   if (ib < 0) ib = i; else ia = i; break;
        case 16:      if (idtb < 0) idtb = i; else ialog = i; break;
        default: break;
      }
    }
  }
  const float* hs   = (const float*)d_in[ih];
  const float* Wqkv = (const float*)d_in[iqkv];
  const float* cw   = (const float*)d_in[icw];
  const float* Wz   = (const float*)d_in[iz];
  const float* Wb   = (const float*)d_in[ib];
  const float* Wa   = (const float*)d_in[ia];
  const float* dtb  = (const float*)d_in[idtb];
  const float* Alog = (const float*)d_in[ialog];
  const float* nwv  = (const float*)d_in[inw];
  const float* Wout = (const float*)d_in[iout];

  // workspace (~68 MiB)
  char* p = (char*)d_ws;
  bf16*  mixed = (bf16*)p;                                 // 32 MiB (gemm1 out)
  float* of    = (float*)p; p += (size_t)M * CDIM_ * 2;    // of fp32 (32 MiB) aliases mixed (dead after conv)
  bf16*  qkvb  = (bf16*)p;                                 // 32 MiB (conv out)
  float* hn    = (float*)p; p += (size_t)M * CDIM_ * 2;    // hn fp32 (32 MiB) aliases qkvb (dead after scan)
  float* betaf = (float*)p; p += (size_t)M * NVH_ * 4;     // 512 KiB
  float* gf    = (float*)p; p += (size_t)M * NVH_ * 4;     // 512 KiB
  float* zb    = out;   // z fp32 staged in d_out (33.5 MB), consumed by gnorm2
                        // before the final gemm overwrites d_out

  // 1) mixed = hs @ Wqkv^T  [8192 x 2048] -> bf16
  vgemm_fb<<<(M / 64) * (CDIM_ / 64), 256, 0, stream>>>(hs, Wqkv, mixed, M, CDIM_, H_);
  // 2) z = hs @ Wz^T  [8192 x 1024] -> fp32 in d_out
  vgemm_ff<<<(M / 64) * (H_ / 64), 256, 0, stream>>>(hs, Wz, zb, M, H_, H_);
  // 3) beta, g (fp32)
  projbg<<<(M * 32) / 256, 256, 0, stream>>>(hs, Wb, Wa, dtb, Alog, betaf, gf);
  // 4) causal depthwise conv + silu + q-scale -> bf16
  conv2<<<(int)(((long)M * CDIM_) / 256), 256, 0, stream>>>(mixed, cw, qkvb);
  // 5) gated delta-rule scan -> of fp32
  scan2<<<B_ * NVH_, 64, 0, stream>>>(qkvb, betaf, gf, of);
  // 6) gated RMSNorm -> hn fp32
  gnorm2<<<(M * NVH_) / 256, 256, 0, stream>>>(of, zb, nwv, hn);
  // 7) out = hn @ Wout^T -> d_out fp32
  vgemm_ff<<<(M / 64) * (H_ / 64), 256, 0, stream>>>(hn, Wout, out, M, H_, H_);
}

// Round 9
// 2806.124 us; speedup vs baseline: 3.1281x; 3.1281x over previous
//
#include <hip/hip_runtime.h>
#include <hip/hip_bf16.h>
#include <stdint.h>

// Problem constants
#define B_    2
#define S_    4096
#define H_    1024
#define NKH_  8
#define NVH_  16
#define DK_   64
#define DV_   64
#define KEYD_ 512          // NKH*DK
#define CDIM_ 2048         // 2*KEYD + VAL_DIM
#define VALD_ 1024         // NVH*DV

using bf16 = __hip_bfloat16;
using bf16x8 = __attribute__((ext_vector_type(8))) short;  // 8 bf16 = 4 VGPRs
using f32x4  = __attribute__((ext_vector_type(4))) float;

__device__ inline float wred64(float x) {
  x += __shfl_xor(x, 1);
  x += __shfl_xor(x, 2);
  x += __shfl_xor(x, 4);
  x += __shfl_xor(x, 8);
  x += __shfl_xor(x, 16);
  x += __shfl_xor(x, 32);
  return x;
}

// ---------------------------------------------------------------------------
// fp32 -> bf16 cast, 4 elems/thread (n % 4 == 0). (r2-validated structure)
// ---------------------------------------------------------------------------
__global__ __launch_bounds__(256) void castf2b(const float* __restrict__ x,
                                               bf16* __restrict__ y, long n) {
  const long i = ((long)blockIdx.x * 256 + threadIdx.x) * 4;
  if (i >= n) return;
  float4 v = *(const float4*)(x + i);
  union { ushort4 u; bf16 h[4]; } o;
  o.h[0] = __float2bfloat16(v.x);
  o.h[1] = __float2bfloat16(v.y);
  o.h[2] = __float2bfloat16(v.z);
  o.h[3] = __float2bfloat16(v.w);
  *(ushort4*)(y + i) = o.u;
}

// ---------------------------------------------------------------------------
// MFMA GEMM (r3 code, end-to-end bit-identical to vgemm at checker):
// C[m,n] = sum_k A[m,k]*B[n,k]; A,B bf16; C bf16 or fp32 (template).
// 128x128 tile, 4 waves 2x2, 4x4 of 16x16x32 MFMA per wave, BK=32,
// register-staged LDS (ds_write_b128). M%128==0, N%128==0, K%32==0.
// ---------------------------------------------------------------------------
template <typename OT>
__global__ __launch_bounds__(256) void gemm_bt(const bf16* __restrict__ A,
                                               const bf16* __restrict__ Bm,
                                               OT* __restrict__ C,
                                               int M, int N, int K) {
  __shared__ short Asm[128 * 32];
  __shared__ short Bsm[128 * 32];
  const int t = threadIdx.x;
  const int w = t >> 6, l = t & 63;
  const int ntn = N >> 7;
  const int bm = blockIdx.x / ntn, bn = blockIdx.x % ntn;
  const int m0 = bm << 7, n0 = bn << 7;
  const int wm = (w >> 1) << 6, wn = (w & 1) << 6;

  f32x4 acc[4][4] = {};

  const int srow = t >> 2;            // 0..63
  const int scol8 = (t & 3) << 3;     // 0,8,16,24
  const bf16* Ag = A + (long)(m0 + srow) * K + scol8;
  const bf16* Bg = Bm + (long)(n0 + srow) * K + scol8;
  const long rstep = (long)64 * K;

  const int lm = l & 15;
  const int kk = (l >> 4) << 3;
  const short* ar0 = &Asm[(wm + lm) * 32 + kk];
  const short* br0 = &Bsm[(wn + lm) * 32 + kk];

  for (int k0 = 0; k0 < K; k0 += 32) {
    bf16x8 a0 = *(const bf16x8*)(Ag + k0);
    bf16x8 a1 = *(const bf16x8*)(Ag + k0 + rstep);
    bf16x8 b0 = *(const bf16x8*)(Bg + k0);
    bf16x8 b1 = *(const bf16x8*)(Bg + k0 + rstep);
    __syncthreads();
    *(bf16x8*)&Asm[srow * 32 + scol8]        = a0;
    *(bf16x8*)&Asm[(64 + srow) * 32 + scol8] = a1;
    *(bf16x8*)&Bsm[srow * 32 + scol8]        = b0;
    *(bf16x8*)&Bsm[(64 + srow) * 32 + scol8] = b1;
    __syncthreads();
    bf16x8 af[4], bfr[4];
#pragma unroll
    for (int mi = 0; mi < 4; ++mi) af[mi] = *(const bf16x8*)(ar0 + mi * 16 * 32);
#pragma unroll
    for (int ni = 0; ni < 4; ++ni) bfr[ni] = *(const bf16x8*)(br0 + ni * 16 * 32);
#pragma unroll
    for (int mi = 0; mi < 4; ++mi)
#pragma unroll
      for (int ni = 0; ni < 4; ++ni)
        acc[mi][ni] = __builtin_amdgcn_mfma_f32_16x16x32_bf16(af[mi], bfr[ni],
                                                              acc[mi][ni], 0, 0, 0);
  }

  // C/D layout: col = l&15, row = (l>>4)*4 + reg
  const int r0 = (l >> 4) << 2;
  const int cn = l & 15;
#pragma unroll
  for (int mi = 0; mi < 4; ++mi)
#pragma unroll
    for (int ni = 0; ni < 4; ++ni) {
      long base = (long)(m0 + wm + mi * 16 + r0) * N + (n0 + wn + ni * 16 + cn);
#pragma unroll
      for (int r = 0; r < 4; ++r) {
        if constexpr (sizeof(OT) == 2)
          C[base + (long)r * N] = __float2bfloat16(acc[mi][ni][r]);
        else
          C[base + (long)r * N] = acc[mi][ni][r];
      }
    }
}

// ---------------------------------------------------------------------------
// conv2 (r8-validated): causal depthwise k=4 cross-corr, silu, q-scale.
// ---------------------------------------------------------------------------
__global__ __launch_bounds__(256) void conv2(const bf16* __restrict__ mixed,
                                             const float* __restrict__ cw,
                                             bf16* __restrict__ qkv) {
  const long idx = (long)blockIdx.x * 256 + threadIdx.x;  // M*2048
  const int c = (int)(idx & (CDIM_ - 1));
  const long row = idx >> 11;
  const int s = (int)(row & (S_ - 1));
  float acc = 0.f;
#pragma unroll
  for (int j = 0; j < 4; ++j) {
    const int ss = s - 3 + j;
    if (ss >= 0)
      acc = fmaf(cw[c * 4 + j], (float)mixed[(row + j - 3) * CDIM_ + c], acc);
  }
  float y = acc / (1.f + __expf(-acc));        // silu
  if (c < KEYD_) y *= 0.125f;                  // q * DK^-0.5
  union { uint16_t u; bf16 h; } o; o.h = __float2bfloat16(y);
  ((uint16_t*)qkv)[row * CDIM_ + c] = o.u;
}

// ---------------------------------------------------------------------------
// proj_ba (r2-validated structure, fp32 hs): beta=sigmoid(hs.Wb), g=-exp(A)*sp.
// block per (b,s) row; 8 threads per output j (32 outputs).
// ---------------------------------------------------------------------------
__global__ __launch_bounds__(256) void proj_ba(const float* __restrict__ hs,
                                               const float* __restrict__ Wb,
                                               const float* __restrict__ Wa,
                                               const float* __restrict__ dtb,
                                               const float* __restrict__ Alog,
                                               float* __restrict__ beta,
                                               float* __restrict__ g) {
  __shared__ float hrow[H_];
  const int row = blockIdx.x;
  const int t = threadIdx.x;
  const float* hp = hs + (long)row * H_;
  for (int i = t; i < H_; i += 256) hrow[i] = hp[i];
  __syncthreads();
  const int j = t >> 3;   // 0..31
  const int p = t & 7;    // 0..7
  const float* Wp = (j < 16) ? (Wb + (long)j * H_) : (Wa + (long)(j - 16) * H_);
  float acc = 0.f;
  for (int i = p; i < H_; i += 8) acc += hrow[i] * Wp[i];
  acc += __shfl_xor(acc, 1);
  acc += __shfl_xor(acc, 2);
  acc += __shfl_xor(acc, 4);
  if (p == 0) {
    if (j < 16) {
      beta[(long)row * NVH_ + j] = 1.f / (1.f + __expf(-acc));
    } else {
      const int hh = j - 16;
      const float x = acc + dtb[hh];
      const float sp = (x > 20.f) ? x : log1pf(__expf(x));
      g[(long)row * NVH_ + hh] = -__expf(Alog[hh]) * sp;
    }
  }
}

// ---------------------------------------------------------------------------
// scan3: dv-parallel gated delta-rule scan. Chain = (b,h,dv) -> 2048 waves.
// lane = dk; state S[dk=lane][dv] is ONE register; two 6-stage shuffle
// reductions per step. Same formulas as r2-r4 scan_kernel (bit-identical to
// scan2 end-to-end), 1 dv/wave for 2 waves/SIMD occupancy.
// ---------------------------------------------------------------------------
__global__ __launch_bounds__(256) void scan3(const bf16* __restrict__ qkv,
                                             const float* __restrict__ beta,
                                             const float* __restrict__ g,
                                             float* __restrict__ o) {
  const int c = blockIdx.x * 4 + (threadIdx.x >> 6);   // 0..2047
  const int l = threadIdx.x & 63;                      // dk
  const int dv = c & 63;
  const int h = (c >> 6) & 15;
  const int b = c >> 10;
  const int kh = h >> 1;                 // GQA repeat_interleave(2)
  const bf16* base = qkv + (long)b * S_ * CDIM_;
  const bf16* qp = base + kh * 64 + l;
  const bf16* kp = base + KEYD_ + kh * 64 + l;
  const bf16* vp = base + 2 * KEYD_ + h * 64 + dv;
  const float* gp = g + (long)b * S_ * NVH_ + h;
  const float* bp = beta + (long)b * S_ * NVH_ + h;
  float* op = o + (long)b * S_ * VALD_ + h * 64 + dv;

  float s = 0.f;
  float kl = (float)kp[0], ql = (float)qp[0], vv = (float)vp[0];
  float gv = gp[0], bv = bp[0];
  for (int t = 0; t < S_; ++t) {
    // prefetch next step before the dependent chain
    const int tn = (t + 1 < S_) ? t + 1 : t;
    const long on = (long)tn * CDIM_;
    float kn = (float)kp[on], qn = (float)qp[on], vn = (float)vp[on];
    float gn = gp[(long)tn * NVH_], bn = bp[(long)tn * NVH_];

    const float eg = __expf(gv);
    const float p = wred64(s * kl);      // (S_old . k) at this dv
    const float d = bv * (vv - eg * p);
    s = fmaf(kl, d, eg * s);
    const float ov = wred64(s * ql);
    if (l == 0) op[(long)t * VALD_] = ov;

    kl = kn; ql = qn; vv = vn; gv = gn; bv = bn;
  }
}

// ---------------------------------------------------------------------------
// gnorm2 (r8-validated structure): h = o*silu(z); rmsnorm; *w -> bf16 hn.
// ---------------------------------------------------------------------------
__global__ __launch_bounds__(256) void gnorm2(const float* __restrict__ o,
                                              const float* __restrict__ z,
                                              const float* __restrict__ nw,
                                              bf16* __restrict__ hn) {
  const long idx = (long)blockIdx.x * 256 + threadIdx.x;  // M*16
  const float* op = o + idx * 64;
  const float* zp = z + idx * 64;
  float hv[64];
  float ss = 0.f;
#pragma unroll
  for (int i = 0; i < 64; ++i) {
    const float zz = zp[i];
    const float hh = op[i] * (zz / (1.f + __expf(-zz)));
    hv[i] = hh;
    ss = fmaf(hh, hh, ss);
  }
  const float r = rsqrtf(ss * (1.f / 64.f) + 1e-6f);
#pragma unroll
  for (int i = 0; i < 64; ++i)
    hn[idx * 64 + i] = __float2bfloat16(hv[i] * r * nw[i]);
}

// ---------------------------------------------------------------------------
extern "C" void kernel_launch(void* const* d_in, const int* in_sizes, int n_in,
                              void* d_out, int out_size, void* d_ws, size_t ws_size,
                              hipStream_t stream) {
  float* out = (float*)d_out;   // fp32 output (r8-confirmed)
  const int M = B_ * S_;        // 8192

  // input mapping (dict order confirmed r7/r8; size-based fallback kept)
  int ih, iqkv, icw, iz, ib, ia, idtb, ialog, inw, iout;
  if (n_in >= 10 && in_sizes[0] == 8388608) {
    ih = 0; iqkv = 1; icw = 2; iz = 3; ib = 4; ia = 5;
    idtb = 6; ialog = 7; inw = 8; iout = 9;
  } else {
    ih = iqkv = icw = iz = ib = ia = idtb = ialog = inw = iout = -1;
    for (int i = 0; i < n_in; ++i) {
      switch (in_sizes[i]) {
        case 8388608: ih = i; break;
        case 2097152: iqkv = i; break;
        case 8192:    icw = i; break;
        case 64:      inw = i; break;
        case 1048576: if (iz < 0) iz = i; else iout = i; break;
        case 16384:   if (ib < 0) ib = i; else ia = i; break;
        case 16:      if (idtb < 0) idtb = i; else ialog = i; break;
        default: break;
      }
    }
  }
  const float* hs   = (const float*)d_in[ih];
  const float* Wqkv = (const float*)d_in[iqkv];
  const float* cw   = (const float*)d_in[icw];
  const float* Wz   = (const float*)d_in[iz];
  const float* Wb   = (const float*)d_in[ib];
  const float* Wa   = (const float*)d_in[ia];
  const float* dtb  = (const float*)d_in[idtb];
  const float* Alog = (const float*)d_in[ialog];
  const float* nwv  = (const float*)d_in[inw];
  const float* Wout = (const float*)d_in[iout];

  // workspace (~73.5 MiB)
  char* p = (char*)d_ws;
  bf16*  mixed = (bf16*)p;                                 // region1: 32 MiB
  float* of    = (float*)p; p += (size_t)M * CDIM_ * 2;    //   of aliases mixed (dead after conv)
  bf16*  hs_b  = (bf16*)p;                                 // region2 start (16 MiB; dead after z-gemm)
  bf16*  qkvb  = (bf16*)p;                                 //   full region2 (conv writes after gemms)
  bf16*  hn    = (bf16*)p; p += (size_t)M * CDIM_ * 2;     //   hn aliases qkvb (dead after scan)
  bf16*  Wqkv_b= (bf16*)p; p += (size_t)CDIM_ * H_ * 2;    // 4 MiB
  bf16*  Wz_b  = (bf16*)p; p += (size_t)H_ * H_ * 2;       // 2 MiB
  bf16*  Wout_b= (bf16*)p; p += (size_t)H_ * H_ * 2;       // 2 MiB
  float* betaf = (float*)p; p += (size_t)M * NVH_ * 4;     // 512 KiB
  float* gf    = (float*)p; p += (size_t)M * NVH_ * 4;     // 512 KiB
  float* zb    = out;   // z fp32 staged in d_out, consumed by gnorm2 before
                        // the final gemm overwrites d_out

  // 0) casts fp32 -> bf16 for MFMA operands
  {
    long n;
    n = (long)M * H_;     castf2b<<<(int)(n / 4 / 256), 256, 0, stream>>>(hs,   hs_b,   n);
    n = (long)CDIM_ * H_; castf2b<<<(int)(n / 4 / 256), 256, 0, stream>>>(Wqkv, Wqkv_b, n);
    n = (long)H_ * H_;    castf2b<<<(int)(n / 4 / 256), 256, 0, stream>>>(Wz,   Wz_b,   n);
    n = (long)H_ * H_;    castf2b<<<(int)(n / 4 / 256), 256, 0, stream>>>(Wout, Wout_b, n);
  }
  // 1) mixed = hs @ Wqkv^T  [8192 x 2048] -> bf16 (MFMA)
  gemm_bt<bf16><<<(M / 128) * (CDIM_ / 128), 256, 0, stream>>>(hs_b, Wqkv_b, mixed, M, CDIM_, H_);
  // 2) z = hs @ Wz^T  [8192 x 1024] -> fp32 in d_out (MFMA)
  gemm_bt<float><<<(M / 128) * (H_ / 128), 256, 0, stream>>>(hs_b, Wz_b, zb, M, H_, H_);
  // 3) beta, g
  proj_ba<<<M, 256, 0, stream>>>(hs, Wb, Wa, dtb, Alog, betaf, gf);
  // 4) causal depthwise conv + silu + q-scale -> bf16 (overwrites hs_b: dead)
  conv2<<<(int)(((long)M * CDIM_) / 256), 256, 0, stream>>>(mixed, cw, qkvb);
  // 5) dv-parallel gated delta-rule scan -> of fp32 (overwrites mixed: dead)
  scan3<<<512, 256, 0, stream>>>(qkvb, betaf, gf, of);
  // 6) gated RMSNorm -> hn bf16 (overwrites qkvb: dead)
  gnorm2<<<(M * NVH_) / 256, 256, 0, stream>>>(of, zb, nwv, hn);
  // 7) out = hn @ Wout^T -> d_out fp32 (MFMA; overwrites z: dead)
  gemm_bt<float><<<(M / 128) * (H_ / 128), 256, 0, stream>>>(hn, Wout_b, out, M, H_, H_);
}

// Round 10
// 1227.635 us; speedup vs baseline: 7.1502x; 2.2858x over previous
//
#include <hip/hip_runtime.h>
#include <hip/hip_bf16.h>
#include <stdint.h>

// Problem constants
#define B_    2
#define S_    4096
#define H_    1024
#define NKH_  8
#define NVH_  16
#define DK_   64
#define DV_   64
#define KEYD_ 512          // NKH*DK
#define CDIM_ 2048         // 2*KEYD + VAL_DIM
#define VALD_ 1024         // NVH*DV

using bf16 = __hip_bfloat16;
using bf16x8 = __attribute__((ext_vector_type(8))) short;  // 8 bf16 = 4 VGPRs
using f32x4  = __attribute__((ext_vector_type(4))) float;

// ---------------------------------------------------------------------------
// DPP wave-wide f32 sum (rocPRIM warp_reduce_dpp sequence). Total lands in
// lane 63. VALU-latency stages — no LDS round-trips on the critical path.
// ---------------------------------------------------------------------------
__device__ inline float dpp_sum64(float x) {
  int v;
  v = __builtin_amdgcn_update_dpp(0, __float_as_int(x), 0x111, 0xf, 0xf, false); // row_shr:1
  x += __int_as_float(v);
  v = __builtin_amdgcn_update_dpp(0, __float_as_int(x), 0x112, 0xf, 0xf, false); // row_shr:2
  x += __int_as_float(v);
  v = __builtin_amdgcn_update_dpp(0, __float_as_int(x), 0x114, 0xf, 0xf, false); // row_shr:4
  x += __int_as_float(v);
  v = __builtin_amdgcn_update_dpp(0, __float_as_int(x), 0x118, 0xf, 0xf, false); // row_shr:8
  x += __int_as_float(v);
  v = __builtin_amdgcn_update_dpp(0, __float_as_int(x), 0x142, 0xf, 0xf, false); // row_bcast:15
  x += __int_as_float(v);
  v = __builtin_amdgcn_update_dpp(0, __float_as_int(x), 0x143, 0xf, 0xf, false); // row_bcast:31
  x += __int_as_float(v);
  return x;  // lane 63 holds the 64-lane total
}

// ---------------------------------------------------------------------------
// fp32 -> bf16 cast, 4 elems/thread (n % 4 == 0). (r2-validated structure)
// ---------------------------------------------------------------------------
__global__ __launch_bounds__(256) void castf2b(const float* __restrict__ x,
                                               bf16* __restrict__ y, long n) {
  const long i = ((long)blockIdx.x * 256 + threadIdx.x) * 4;
  if (i >= n) return;
  float4 v = *(const float4*)(x + i);
  union { ushort4 u; bf16 h[4]; } o;
  o.h[0] = __float2bfloat16(v.x);
  o.h[1] = __float2bfloat16(v.y);
  o.h[2] = __float2bfloat16(v.z);
  o.h[3] = __float2bfloat16(v.w);
  *(ushort4*)(y + i) = o.u;
}

// ---------------------------------------------------------------------------
// MFMA GEMM (r9-validated): C[m,n] = sum_k A[m,k]*B[n,k]; A,B bf16;
// C bf16 or fp32. 128x128 tile, 4 waves 2x2, 4x4 of 16x16x32 MFMA, BK=32.
// ---------------------------------------------------------------------------
template <typename OT>
__global__ __launch_bounds__(256) void gemm_bt(const bf16* __restrict__ A,
                                               const bf16* __restrict__ Bm,
                                               OT* __restrict__ C,
                                               int M, int N, int K) {
  __shared__ short Asm[128 * 32];
  __shared__ short Bsm[128 * 32];
  const int t = threadIdx.x;
  const int w = t >> 6, l = t & 63;
  const int ntn = N >> 7;
  const int bm = blockIdx.x / ntn, bn = blockIdx.x % ntn;
  const int m0 = bm << 7, n0 = bn << 7;
  const int wm = (w >> 1) << 6, wn = (w & 1) << 6;

  f32x4 acc[4][4] = {};

  const int srow = t >> 2;            // 0..63
  const int scol8 = (t & 3) << 3;     // 0,8,16,24
  const bf16* Ag = A + (long)(m0 + srow) * K + scol8;
  const bf16* Bg = Bm + (long)(n0 + srow) * K + scol8;
  const long rstep = (long)64 * K;

  const int lm = l & 15;
  const int kk = (l >> 4) << 3;
  const short* ar0 = &Asm[(wm + lm) * 32 + kk];
  const short* br0 = &Bsm[(wn + lm) * 32 + kk];

  for (int k0 = 0; k0 < K; k0 += 32) {
    bf16x8 a0 = *(const bf16x8*)(Ag + k0);
    bf16x8 a1 = *(const bf16x8*)(Ag + k0 + rstep);
    bf16x8 b0 = *(const bf16x8*)(Bg + k0);
    bf16x8 b1 = *(const bf16x8*)(Bg + k0 + rstep);
    __syncthreads();
    *(bf16x8*)&Asm[srow * 32 + scol8]        = a0;
    *(bf16x8*)&Asm[(64 + srow) * 32 + scol8] = a1;
    *(bf16x8*)&Bsm[srow * 32 + scol8]        = b0;
    *(bf16x8*)&Bsm[(64 + srow) * 32 + scol8] = b1;
    __syncthreads();
    bf16x8 af[4], bfr[4];
#pragma unroll
    for (int mi = 0; mi < 4; ++mi) af[mi] = *(const bf16x8*)(ar0 + mi * 16 * 32);
#pragma unroll
    for (int ni = 0; ni < 4; ++ni) bfr[ni] = *(const bf16x8*)(br0 + ni * 16 * 32);
#pragma unroll
    for (int mi = 0; mi < 4; ++mi)
#pragma unroll
      for (int ni = 0; ni < 4; ++ni)
        acc[mi][ni] = __builtin_amdgcn_mfma_f32_16x16x32_bf16(af[mi], bfr[ni],
                                                              acc[mi][ni], 0, 0, 0);
  }

  // C/D layout: col = l&15, row = (l>>4)*4 + reg
  const int r0 = (l >> 4) << 2;
  const int cn = l & 15;
#pragma unroll
  for (int mi = 0; mi < 4; ++mi)
#pragma unroll
    for (int ni = 0; ni < 4; ++ni) {
      long base = (long)(m0 + wm + mi * 16 + r0) * N + (n0 + wn + ni * 16 + cn);
#pragma unroll
      for (int r = 0; r < 4; ++r) {
        if constexpr (sizeof(OT) == 2)
          C[base + (long)r * N] = __float2bfloat16(acc[mi][ni][r]);
        else
          C[base + (long)r * N] = acc[mi][ni][r];
      }
    }
}

// ---------------------------------------------------------------------------
// conv2 (r8/r9-validated): causal depthwise k=4 cross-corr, silu, q-scale.
// ---------------------------------------------------------------------------
__global__ __launch_bounds__(256) void conv2(const bf16* __restrict__ mixed,
                                             const float* __restrict__ cw,
                                             bf16* __restrict__ qkv) {
  const long idx = (long)blockIdx.x * 256 + threadIdx.x;  // M*2048
  const int c = (int)(idx & (CDIM_ - 1));
  const long row = idx >> 11;
  const int s = (int)(row & (S_ - 1));
  float acc = 0.f;
#pragma unroll
  for (int j = 0; j < 4; ++j) {
    const int ss = s - 3 + j;
    if (ss >= 0)
      acc = fmaf(cw[c * 4 + j], (float)mixed[(row + j - 3) * CDIM_ + c], acc);
  }
  float y = acc / (1.f + __expf(-acc));        // silu
  if (c < KEYD_) y *= 0.125f;                  // q * DK^-0.5
  union { uint16_t u; bf16 h; } o; o.h = __float2bfloat16(y);
  ((uint16_t*)qkv)[row * CDIM_ + c] = o.u;
}

// ---------------------------------------------------------------------------
// proj_ba (r9-validated): beta=sigmoid(hs.Wb), g=-exp(A)*softplus(hs.Wa+dtb).
// ---------------------------------------------------------------------------
__global__ __launch_bounds__(256) void proj_ba(const float* __restrict__ hs,
                                               const float* __restrict__ Wb,
                                               const float* __restrict__ Wa,
                                               const float* __restrict__ dtb,
                                               const float* __restrict__ Alog,
                                               float* __restrict__ beta,
                                               float* __restrict__ g) {
  __shared__ float hrow[H_];
  const int row = blockIdx.x;
  const int t = threadIdx.x;
  const float* hp = hs + (long)row * H_;
  for (int i = t; i < H_; i += 256) hrow[i] = hp[i];
  __syncthreads();
  const int j = t >> 3;   // 0..31
  const int p = t & 7;    // 0..7
  const float* Wp = (j < 16) ? (Wb + (long)j * H_) : (Wa + (long)(j - 16) * H_);
  float acc = 0.f;
  for (int i = p; i < H_; i += 8) acc += hrow[i] * Wp[i];
  acc += __shfl_xor(acc, 1);
  acc += __shfl_xor(acc, 2);
  acc += __shfl_xor(acc, 4);
  if (p == 0) {
    if (j < 16) {
      beta[(long)row * NVH_ + j] = 1.f / (1.f + __expf(-acc));
    } else {
      const int hh = j - 16;
      const float x = acc + dtb[hh];
      const float sp = (x > 20.f) ? x : log1pf(__expf(x));
      g[(long)row * NVH_ + hh] = -__expf(Alog[hh]) * sp;
    }
  }
}

// ---------------------------------------------------------------------------
// scan4: dv-parallel scan, DPP reductions. Chain = (b,h,dv) -> 2048 waves,
// lane = dk, state = 1 register. Per-step critical path: 2 DPP sums +
// readlane + 2 FMA (exp/beta products precomputed at prefetch, depth-4
// circular prefetch covers L2 latency).
// ---------------------------------------------------------------------------
__global__ __launch_bounds__(256) void scan4(const bf16* __restrict__ qkv,
                                             const float* __restrict__ beta,
                                             const float* __restrict__ g,
                                             float* __restrict__ o) {
  const int c = blockIdx.x * 4 + (threadIdx.x >> 6);   // chain id 0..2047
  const int l = threadIdx.x & 63;                      // dk
  const int dv = c & 63;
  const int h = (c >> 6) & 15;
  const int b = c >> 10;
  const int kh = h >> 1;                 // GQA repeat_interleave(2)
  const bf16* base = qkv + (long)b * S_ * CDIM_;
  const bf16* qp = base + kh * 64 + l;
  const bf16* kp = base + KEYD_ + kh * 64 + l;
  const bf16* vp = base + 2 * KEYD_ + h * 64 + dv;
  const float* gp = g + (long)b * S_ * NVH_ + h;
  const float* bp = beta + (long)b * S_ * NVH_ + h;
  float* op = o + (long)b * S_ * VALD_ + h * 64 + dv;

  // depth-4 circular prefetch buffers
  float kb_[4], qb_[4], eb_[4], begb_[4], bvvb_[4];
#pragma unroll
  for (int i = 0; i < 4; ++i) {
    const long on = (long)i * CDIM_;
    kb_[i] = (float)kp[on];
    qb_[i] = (float)qp[on];
    const float vv = (float)vp[on];
    const float eg = __expf(gp[(long)i * NVH_]);
    const float bv = bp[(long)i * NVH_];
    eb_[i] = eg; begb_[i] = bv * eg; bvvb_[i] = bv * vv;
  }

  float s = 0.f;
#pragma unroll 4
  for (int t = 0; t < S_; ++t) {
    const int sl = t & 3;
    const float kl = kb_[sl], ql = qb_[sl];
    const float eg = eb_[sl], beg = begb_[sl], bvv = bvvb_[sl];

    // prefetch t+4 (off critical path; exp + beta products here too)
    {
      int tn = t + 4; if (tn >= S_) tn = S_ - 1;
      const long on = (long)tn * CDIM_;
      kb_[sl] = (float)kp[on];
      qb_[sl] = (float)qp[on];
      const float vvn = (float)vp[on];
      const float egn = __expf(gp[(long)tn * NVH_]);
      const float bvn = bp[(long)tn * NVH_];
      eb_[sl] = egn; begb_[sl] = bvn * egn; bvvb_[sl] = bvn * vvn;
    }

    const float egs = eg * s;                 // parallel to reduction
    const float P = dpp_sum64(s * kl);        // (S_old . k), lane 63
    const float p = __int_as_float(__builtin_amdgcn_readlane(__float_as_int(P), 63));
    const float d = fmaf(-beg, p, bvv);       // beta*(v - eg*p)
    s = fmaf(kl, d, egs);                     // S = eg*S + k (x) d
    const float OV = dpp_sum64(s * ql);       // (S_new . q), lane 63
    if (l == 63) op[(long)t * VALD_] = OV;
  }
}

// ---------------------------------------------------------------------------
// gnorm2 (r9-validated): h = o*silu(z); rmsnorm; *w -> bf16 hn.
// ---------------------------------------------------------------------------
__global__ __launch_bounds__(256) void gnorm2(const float* __restrict__ o,
                                              const float* __restrict__ z,
                                              const float* __restrict__ nw,
                                              bf16* __restrict__ hn) {
  const long idx = (long)blockIdx.x * 256 + threadIdx.x;  // M*16
  const float* op = o + idx * 64;
  const float* zp = z + idx * 64;
  float hv[64];
  float ss = 0.f;
#pragma unroll
  for (int i = 0; i < 64; ++i) {
    const float zz = zp[i];
    const float hh = op[i] * (zz / (1.f + __expf(-zz)));
    hv[i] = hh;
    ss = fmaf(hh, hh, ss);
  }
  const float r = rsqrtf(ss * (1.f / 64.f) + 1e-6f);
#pragma unroll
  for (int i = 0; i < 64; ++i)
    hn[idx * 64 + i] = __float2bfloat16(hv[i] * r * nw[i]);
}

// ---------------------------------------------------------------------------
extern "C" void kernel_launch(void* const* d_in, const int* in_sizes, int n_in,
                              void* d_out, int out_size, void* d_ws, size_t ws_size,
                              hipStream_t stream) {
  float* out = (float*)d_out;   // fp32 output (r8-confirmed)
  const int M = B_ * S_;        // 8192

  // input mapping (dict order confirmed; size-based fallback kept)
  int ih, iqkv, icw, iz, ib, ia, idtb, ialog, inw, iout;
  if (n_in >= 10 && in_sizes[0] == 8388608) {
    ih = 0; iqkv = 1; icw = 2; iz = 3; ib = 4; ia = 5;
    idtb = 6; ialog = 7; inw = 8; iout = 9;
  } else {
    ih = iqkv = icw = iz = ib = ia = idtb = ialog = inw = iout = -1;
    for (int i = 0; i < n_in; ++i) {
      switch (in_sizes[i]) {
        case 8388608: ih = i; break;
        case 2097152: iqkv = i; break;
        case 8192:    icw = i; break;
        case 64:      inw = i; break;
        case 1048576: if (iz < 0) iz = i; else iout = i; break;
        case 16384:   if (ib < 0) ib = i; else ia = i; break;
        case 16:      if (idtb < 0) idtb = i; else ialog = i; break;
        default: break;
      }
    }
  }
  const float* hs   = (const float*)d_in[ih];
  const float* Wqkv = (const float*)d_in[iqkv];
  const float* cw   = (const float*)d_in[icw];
  const float* Wz   = (const float*)d_in[iz];
  const float* Wb   = (const float*)d_in[ib];
  const float* Wa   = (const float*)d_in[ia];
  const float* dtb  = (const float*)d_in[idtb];
  const float* Alog = (const float*)d_in[ialog];
  const float* nwv  = (const float*)d_in[inw];
  const float* Wout = (const float*)d_in[iout];

  // workspace (~73.5 MiB), layout identical to r9
  char* p = (char*)d_ws;
  bf16*  mixed = (bf16*)p;                                 // region1: 32 MiB
  float* of    = (float*)p; p += (size_t)M * CDIM_ * 2;    //   of aliases mixed
  bf16*  hs_b  = (bf16*)p;                                 // region2 (16 MiB; dead after z-gemm)
  bf16*  qkvb  = (bf16*)p;                                 //   full region2
  bf16*  hn    = (bf16*)p; p += (size_t)M * CDIM_ * 2;     //   hn aliases qkvb
  bf16*  Wqkv_b= (bf16*)p; p += (size_t)CDIM_ * H_ * 2;    // 4 MiB
  bf16*  Wz_b  = (bf16*)p; p += (size_t)H_ * H_ * 2;       // 2 MiB
  bf16*  Wout_b= (bf16*)p; p += (size_t)H_ * H_ * 2;       // 2 MiB
  float* betaf = (float*)p; p += (size_t)M * NVH_ * 4;     // 512 KiB
  float* gf    = (float*)p; p += (size_t)M * NVH_ * 4;     // 512 KiB
  float* zb    = out;   // z fp32 staged in d_out, consumed by gnorm2

  // 0) casts fp32 -> bf16 for MFMA operands
  {
    long n;
    n = (long)M * H_;     castf2b<<<(int)(n / 4 / 256), 256, 0, stream>>>(hs,   hs_b,   n);
    n = (long)CDIM_ * H_; castf2b<<<(int)(n / 4 / 256), 256, 0, stream>>>(Wqkv, Wqkv_b, n);
    n = (long)H_ * H_;    castf2b<<<(int)(n / 4 / 256), 256, 0, stream>>>(Wz,   Wz_b,   n);
    n = (long)H_ * H_;    castf2b<<<(int)(n / 4 / 256), 256, 0, stream>>>(Wout, Wout_b, n);
  }
  // 1) mixed = hs @ Wqkv^T  [8192 x 2048] -> bf16 (MFMA)
  gemm_bt<bf16><<<(M / 128) * (CDIM_ / 128), 256, 0, stream>>>(hs_b, Wqkv_b, mixed, M, CDIM_, H_);
  // 2) z = hs @ Wz^T  [8192 x 1024] -> fp32 in d_out (MFMA)
  gemm_bt<float><<<(M / 128) * (H_ / 128), 256, 0, stream>>>(hs_b, Wz_b, zb, M, H_, H_);
  // 3) beta, g
  proj_ba<<<M, 256, 0, stream>>>(hs, Wb, Wa, dtb, Alog, betaf, gf);
  // 4) causal depthwise conv + silu + q-scale -> bf16
  conv2<<<(int)(((long)M * CDIM_) / 256), 256, 0, stream>>>(mixed, cw, qkvb);
  // 5) dv-parallel gated delta-rule scan (DPP) -> of fp32
  scan4<<<512, 256, 0, stream>>>(qkvb, betaf, gf, of);
  // 6) gated RMSNorm -> hn bf16
  gnorm2<<<(M * NVH_) / 256, 256, 0, stream>>>(of, zb, nwv, hn);
  // 7) out = hn @ Wout^T -> d_out fp32 (MFMA)
  gemm_bt<float><<<(M / 128) * (H_ / 128), 256, 0, stream>>>(hn, Wout_b, out, M, H_, H_);
}